// Round 2
// baseline (831.019 us; speedup 1.0000x reference)
//
#include <hip/hip_runtime.h>
#include <stdint.h>

constexpr int D_DIM   = 128;   // embedding dim
constexpr int C_CELLS = 1024;  // cells (32*32)
constexpr float EPS_D = 5e-3f; // suspect gap threshold (distance units)

typedef __attribute__((ext_vector_type(8))) short  short8;
typedef __attribute__((ext_vector_type(4))) float  floatx4;

__device__ __forceinline__ unsigned short f32_bf16_rtn(float x) {
    union { float f; unsigned u; } v; v.f = x;
    unsigned r = v.u + 0x7FFFu + ((v.u >> 16) & 1u);
    return (unsigned short)(r >> 16);
}
__device__ __forceinline__ float bf16_f32(unsigned short h) {
    union { float f; unsigned u; } v; v.u = ((unsigned)h) << 16; return v.f;
}
__device__ __forceinline__ float hi_f32(unsigned long long p) {
    union { float f; unsigned u; } v; v.u = (unsigned)(p >> 32); return v.f;
}

// ---------------- init: win=-1, flag=1, suspCount=0 ----------------
__global__ void init_kernel(int* win, int* flag, int* suspCount, int numNodes) {
    int j = blockIdx.x * blockDim.x + threadIdx.x;
    if (j < numNodes) win[j] = -1;
    if (j == 0) { *flag = 1; *suspCount = 0; }
}

// ------------- dtype probe: int64 nodes have all odd 32-bit words == 0 -------------
__global__ void detect_kernel(const int* nodes32, int n, int* flag) {
    int i = blockIdx.x * blockDim.x + threadIdx.x;
    if (i < n && (i & 1) && nodes32[i] != 0) *flag = 0;   // int32 data detected
}

// ------------- last-write-wins: winning batch index per node -------------
__global__ void winner_kernel(const void* nodes, int n, const int* flag, int* win) {
    int i = blockIdx.x * blockDim.x + threadIdx.x;
    if (i >= n) return;
    int node = (*flag) ? (int)((const long long*)nodes)[i]
                       : ((const int*)nodes)[i];
    atomicMax(&win[node], i);
}

// ------------- row squared norms (wave per row, D=128 = 64 lanes x float2) -------------
__global__ void norms_kernel(const float* __restrict__ v, float* __restrict__ o, int rows) {
    int row  = blockIdx.x * 4 + (threadIdx.x >> 6);
    int lane = threadIdx.x & 63;
    if (row >= rows) return;
    float2 x = reinterpret_cast<const float2*>(v)[(size_t)row * 64 + lane];
    float s = x.x * x.x + x.y * x.y;
    #pragma unroll
    for (int m = 32; m; m >>= 1) s += __shfl_xor(s, m, 64);
    if (lane == 0) o[row] = s;
}

// ------------- main: split-bf16 MFMA cdist + top-2 argmin + suspect list -------------
__global__ __launch_bounds__(256, 2)
void dist_kernel(const float* __restrict__ X, const float* __restrict__ M,
                 const float* __restrict__ xsq, const float* __restrict__ msq,
                 float* __restrict__ outD, int* __restrict__ cells32,
                 int* __restrict__ suspects, int* __restrict__ suspCount,
                 int N)
{
    __shared__ __align__(16) unsigned short Ah[64 * 128];
    __shared__ __align__(16) unsigned short Al[64 * 128];
    __shared__ __align__(16) unsigned short Bh[64 * 128];
    __shared__ __align__(16) unsigned short Bl[64 * 128];
    __shared__ unsigned long long sp1[64][2];
    __shared__ float              sm2[64][2];

    const int tid  = threadIdx.x;
    const int lane = tid & 63;
    const int wave = tid >> 6;
    const int q    = lane >> 4;    // quad id (0..3)
    const int l15  = lane & 15;
    const int w0   = wave & 1;     // col half (0..1)
    const int w1   = wave >> 1;    // row half (0..1)
    const int blockRow = blockIdx.x * 64;

    // ---- stage A: 64 rows x 128 k, f32 -> bf16 hi/lo, swizzled ----
    #pragma unroll
    for (int p = 0; p < 4; ++p) {
        int r = p * 16 + (tid >> 4);    // 0..63
        int b = tid & 15;               // 16-byte block index (8 bf16)
        int gRow = blockRow + r;
        float4 v0 = make_float4(0.f, 0.f, 0.f, 0.f), v1 = v0;
        if (gRow < N) {
            const float4* s = reinterpret_cast<const float4*>(X + (size_t)gRow * D_DIM + b * 8);
            v0 = s[0]; v1 = s[1];
        }
        float xv[8] = { v0.x, v0.y, v0.z, v0.w, v1.x, v1.y, v1.z, v1.w };
        short8 hs, ls;
        #pragma unroll
        for (int j = 0; j < 8; ++j) {
            unsigned short hb = f32_bf16_rtn(xv[j]);
            unsigned short lb = f32_bf16_rtn(xv[j] - bf16_f32(hb));
            hs[j] = (short)hb; ls[j] = (short)lb;
        }
        int ad = r * 128 + ((b ^ (r & 15)) << 3);
        *reinterpret_cast<short8*>(&Ah[ad]) = hs;
        *reinterpret_cast<short8*>(&Al[ad]) = ls;
    }

    // per-lane fixed output rows: g(t,r) = blockRow + w1*32 + t*16 + q*4 + r
    float xs[8];
    #pragma unroll
    for (int t = 0; t < 2; ++t)
        #pragma unroll
        for (int r = 0; r < 4; ++r) {
            int g = blockRow + w1 * 32 + t * 16 + q * 4 + r;
            xs[t * 4 + r] = (g < N) ? xsq[g] : 0.f;
        }

    float rminv[8]; float rmin2[8]; int rminc[8];
    #pragma unroll
    for (int i = 0; i < 8; ++i) { rminv[i] = INFINITY; rmin2[i] = INFINITY; rminc[i] = 0; }

    for (int ct = 0; ct < 16; ++ct) {
        __syncthreads();   // previous tile's LDS reads done (also covers A staging)
        // ---- stage B: 64 cells x 128 k ----
        #pragma unroll
        for (int p = 0; p < 4; ++p) {
            int r = p * 16 + (tid >> 4);
            int b = tid & 15;
            int gCol = ct * 64 + r;
            const float4* s = reinterpret_cast<const float4*>(M + (size_t)gCol * D_DIM + b * 8);
            float4 v0 = s[0], v1 = s[1];
            float xv[8] = { v0.x, v0.y, v0.z, v0.w, v1.x, v1.y, v1.z, v1.w };
            short8 hs, ls;
            #pragma unroll
            for (int j = 0; j < 8; ++j) {
                unsigned short hb = f32_bf16_rtn(xv[j]);
                unsigned short lb = f32_bf16_rtn(xv[j] - bf16_f32(hb));
                hs[j] = (short)hb; ls[j] = (short)lb;
            }
            int ad = r * 128 + ((b ^ (r & 15)) << 3);
            *reinterpret_cast<short8*>(&Bh[ad]) = hs;
            *reinterpret_cast<short8*>(&Bl[ad]) = ls;
        }
        __syncthreads();

        floatx4 acc[2][2];
        #pragma unroll
        for (int t = 0; t < 2; ++t)
            #pragma unroll
            for (int u = 0; u < 2; ++u)
                acc[t][u] = (floatx4){0.f, 0.f, 0.f, 0.f};

        #pragma unroll
        for (int kc = 0; kc < 4; ++kc) {
            int blk = kc * 4 + q;
            short8 ah[2], al[2], bh[2], bl[2];
            #pragma unroll
            for (int t = 0; t < 2; ++t) {
                int row = w1 * 32 + t * 16 + l15;     // row & 15 == l15
                int ad  = row * 128 + ((blk ^ l15) << 3);
                ah[t] = *reinterpret_cast<const short8*>(&Ah[ad]);
                al[t] = *reinterpret_cast<const short8*>(&Al[ad]);
            }
            #pragma unroll
            for (int u = 0; u < 2; ++u) {
                int col = w0 * 32 + u * 16 + l15;
                int ad  = col * 128 + ((blk ^ l15) << 3);
                bh[u] = *reinterpret_cast<const short8*>(&Bh[ad]);
                bl[u] = *reinterpret_cast<const short8*>(&Bl[ad]);
            }
            #pragma unroll
            for (int t = 0; t < 2; ++t)
                #pragma unroll
                for (int u = 0; u < 2; ++u) {
                    acc[t][u] = __builtin_amdgcn_mfma_f32_16x16x32_bf16(ah[t], bh[u], acc[t][u], 0, 0, 0);
                    acc[t][u] = __builtin_amdgcn_mfma_f32_16x16x32_bf16(ah[t], bl[u], acc[t][u], 0, 0, 0);
                    acc[t][u] = __builtin_amdgcn_mfma_f32_16x16x32_bf16(al[t], bh[u], acc[t][u], 0, 0, 0);
                }
        }

        // ---- epilogue: sq = |x|^2 + |m|^2 - 2*dot ; dist, store, running top-2 ----
        #pragma unroll
        for (int u = 0; u < 2; ++u) {
            int col = ct * 64 + w0 * 32 + u * 16 + l15;
            float ms = msq[col];
            #pragma unroll
            for (int t = 0; t < 2; ++t)
                #pragma unroll
                for (int r = 0; r < 4; ++r) {
                    int g  = blockRow + w1 * 32 + t * 16 + q * 4 + r;
                    int i  = t * 4 + r;
                    float sq = xs[i] + ms - 2.0f * acc[t][u][r];
                    float d  = sqrtf(fmaxf(sq, 0.0f));
                    if (g < N) outD[(size_t)g * C_CELLS + col] = d;
                    if (d < rminv[i]) { rmin2[i] = rminv[i]; rminv[i] = d; rminc[i] = col; }
                    else if (d < rmin2[i]) rmin2[i] = d;
                }
        }
    }

    // ---- per-row top-2 reduce across the 16 lanes sharing the same rows ----
    #pragma unroll
    for (int i = 0; i < 8; ++i) {
        union { float f; unsigned u; } bu; bu.f = rminv[i];
        unsigned long long p1 = ((unsigned long long)bu.u << 32) | (unsigned)rminc[i];
        float m2 = rmin2[i];
        #pragma unroll
        for (int m = 1; m < 16; m <<= 1) {
            unsigned long long o1 = __shfl_xor(p1, m, 16);
            float o2 = __shfl_xor(m2, m, 16);
            unsigned long long hi = (p1 > o1) ? p1 : o1;
            float hv = hi_f32(hi);
            p1 = (p1 < o1) ? p1 : o1;
            m2 = fminf(fminf(m2, o2), hv);
        }
        if (l15 == 0) {
            int lr = w1 * 32 + (i >> 2) * 16 + q * 4 + (i & 3);
            sp1[lr][w0] = p1; sm2[lr][w0] = m2;
        }
    }
    __syncthreads();
    // ---- cross-wave merge: one thread per row; write cell + suspect test ----
    if (tid < 64) {
        int g = blockRow + tid;
        if (g < N) {
            unsigned long long a = sp1[tid][0], b = sp1[tid][1];
            unsigned long long G1 = (a < b) ? a : b;
            unsigned long long hi = (a < b) ? b : a;
            float M2  = fminf(fminf(sm2[tid][0], sm2[tid][1]), hi_f32(hi));
            float g1v = hi_f32(G1);
            cells32[g] = (int)(G1 & 0xffffffffu);
            if (M2 - g1v < EPS_D) {
                int ix = atomicAdd(suspCount, 1);
                suspects[ix] = g;
            }
        }
    }
}

// ------------- refine: exact f64 argmin for near-tie rows -------------
__global__ __launch_bounds__(256)
void refine_kernel(const float* __restrict__ X, const float* __restrict__ M,
                   const int* __restrict__ suspects, const int* __restrict__ suspCount,
                   int* __restrict__ cells32)
{
    __shared__ double xd[128];
    __shared__ unsigned long long wres[4];
    int cnt = *suspCount;
    for (int s = blockIdx.x; s < cnt; s += gridDim.x) {
        int row = suspects[s];
        if (threadIdx.x < 128) xd[threadIdx.x] = (double)X[(size_t)row * D_DIM + threadIdx.x];
        __syncthreads();
        unsigned long long best = ~0ull;
        for (int c = threadIdx.x; c < C_CELLS; c += 256) {
            const float* mp = M + (size_t)c * D_DIM;
            double acc = 0.0;
            #pragma unroll 4
            for (int k = 0; k < D_DIM; ++k) {
                double diff = xd[k] - (double)mp[k];
                acc = fma(diff, diff, acc);
            }
            // positive doubles: bit pattern is order-preserving; low 10 bits -> col (tie -> lower col)
            unsigned long long bits = (unsigned long long)__double_as_longlong(acc);
            unsigned long long pk = (bits & ~1023ull) | (unsigned long long)c;
            if (pk < best) best = pk;
        }
        #pragma unroll
        for (int m = 32; m; m >>= 1) {
            unsigned long long o = __shfl_xor(best, m, 64);
            if (o < best) best = o;
        }
        if ((threadIdx.x & 63) == 0) wres[threadIdx.x >> 6] = best;
        __syncthreads();
        if (threadIdx.x == 0) {
            unsigned long long b0 = wres[0] < wres[1] ? wres[0] : wres[1];
            unsigned long long b1 = wres[2] < wres[3] ? wres[2] : wres[3];
            unsigned long long b  = b0 < b1 ? b0 : b1;
            cells32[row] = (int)(b & 1023ull);
        }
        __syncthreads();
    }
}

// ------------- finalize: cells + scatter outputs (all written as f32 values) -------------
__global__ void post_kernel(const int* __restrict__ cells32,
                            const int* __restrict__ win,
                            const float* __restrict__ times,
                            const int* __restrict__ node_cell,
                            const float* __restrict__ node_time,
                            float* __restrict__ outCells,
                            float* __restrict__ outNC,
                            float* __restrict__ outNT,
                            int n, int numNodes)
{
    int j = blockIdx.x * blockDim.x + threadIdx.x;
    if (j < n) outCells[j] = (float)cells32[j];
    if (j < numNodes) {
        int w = win[j];
        float c, t;
        if (w >= 0) {
            c = (float)cells32[w];
            t = times[w];
        } else {
            c = (float)node_cell[j];
            t = node_time[j];
        }
        outNC[j] = c;
        outNT[j] = t;
    }
}

extern "C" void kernel_launch(void* const* d_in, const int* in_sizes, int n_in,
                              void* d_out, int out_size, void* d_ws, size_t ws_size,
                              hipStream_t stream)
{
    const float* X         = (const float*)d_in[0];   // [N, 128]
    const float* M         = (const float*)d_in[1];   // [1024, 128]
    const void*  nodes     = d_in[2];                 // [N] int32 or int64
    const float* times     = (const float*)d_in[3];   // [N]
    const int*   node_cell = (const int*)d_in[4];     // [numNodes]
    const float* node_time = (const float*)d_in[5];   // [numNodes]

    const int N        = in_sizes[3];
    const int numNodes = in_sizes[4];
    const int C        = in_sizes[1] / D_DIM;         // 1024

    // workspace layout (~5.2 MB)
    char* ws = (char*)d_ws;
    size_t off = 0;
    int* win      = (int*)(ws + off); off += (size_t)numNodes * 4;
    int* cells32  = (int*)(ws + off); off += (size_t)N * 4;
    int* suspects = (int*)(ws + off); off += (size_t)N * 4;
    float* xsq    = (float*)(ws + off); off += (size_t)N * 4;
    float* msq    = (float*)(ws + off); off += (size_t)C * 4;
    int* flag     = (int*)(ws + off); off += 4;
    int* suspCount= (int*)(ws + off); off += 4;
    (void)ws_size; (void)n_in; (void)out_size;

    float* outD     = (float*)d_out;                  // [N,1024] distances
    float* outCells = outD + (size_t)N * C;           // [N] cells (as f32)
    float* outNC    = outCells + N;                   // [numNodes] node_cell (as f32)
    float* outNT    = outNC + numNodes;               // [numNodes] node_time

    init_kernel  <<<(numNodes + 255) / 256, 256, 0, stream>>>(win, flag, suspCount, numNodes);
    detect_kernel<<<(N + 255) / 256, 256, 0, stream>>>((const int*)nodes, N, flag);
    winner_kernel<<<(N + 255) / 256, 256, 0, stream>>>(nodes, N, flag, win);
    norms_kernel <<<(N + 3) / 4, 256, 0, stream>>>(X, xsq, N);
    norms_kernel <<<(C + 3) / 4, 256, 0, stream>>>(M, msq, C);
    dist_kernel  <<<(N + 63) / 64, 256, 0, stream>>>(X, M, xsq, msq, outD, cells32,
                                                     suspects, suspCount, N);
    refine_kernel<<<512, 256, 0, stream>>>(X, M, suspects, suspCount, cells32);
    post_kernel  <<<(numNodes + 255) / 256, 256, 0, stream>>>(cells32, win, times, node_cell,
                                                              node_time, outCells, outNC, outNT,
                                                              N, numNodes);
}

// Round 3
// 723.059 us; speedup vs baseline: 1.1493x; 1.1493x over previous
//
#include <hip/hip_runtime.h>
#include <stdint.h>

constexpr int D_DIM   = 128;    // embedding dim
constexpr int C_CELLS = 1024;   // cells (32*32)
constexpr float EPS_D = 1.5e-3f; // suspect gap threshold (distance units)

typedef __attribute__((ext_vector_type(8))) short  short8;
typedef __attribute__((ext_vector_type(4))) float  floatx4;

#define GLOBAL_AS __attribute__((address_space(1)))
#define LDS_AS    __attribute__((address_space(3)))

__device__ __forceinline__ void gl2lds16(const void* g, void* l) {
    __builtin_amdgcn_global_load_lds((const GLOBAL_AS unsigned int*)g,
                                     (LDS_AS unsigned int*)l, 16, 0, 0);
}

__device__ __forceinline__ unsigned short f32_bf16_rtn(float x) {
    union { float f; unsigned u; } v; v.f = x;
    unsigned r = v.u + 0x7FFFu + ((v.u >> 16) & 1u);
    return (unsigned short)(r >> 16);
}
__device__ __forceinline__ float bf16_f32(unsigned short h) {
    union { float f; unsigned u; } v; v.u = ((unsigned)h) << 16; return v.f;
}
__device__ __forceinline__ float hi_f32(unsigned long long p) {
    union { float f; unsigned u; } v; v.u = (unsigned)(p >> 32); return v.f;
}

// ---------------- init: win=-1, flag=1, suspCount=0 ----------------
__global__ void init_kernel(int* win, int* flag, int* suspCount, int numNodes) {
    int j = blockIdx.x * blockDim.x + threadIdx.x;
    if (j < numNodes) win[j] = -1;
    if (j == 0) { *flag = 1; *suspCount = 0; }
}

// ------------- dtype probe: int64 nodes have all odd 32-bit words == 0 -------------
__global__ void detect_kernel(const int* nodes32, int n, int* flag) {
    int i = blockIdx.x * blockDim.x + threadIdx.x;
    if (i < n && (i & 1) && nodes32[i] != 0) *flag = 0;   // int32 data detected
}

// ------------- last-write-wins: winning batch index per node -------------
__global__ void winner_kernel(const void* nodes, int n, const int* flag, int* win) {
    int i = blockIdx.x * blockDim.x + threadIdx.x;
    if (i >= n) return;
    int node = (*flag) ? (int)((const long long*)nodes)[i]
                       : ((const int*)nodes)[i];
    atomicMax(&win[node], i);
}

// ------------- M squared norms (wave per row) -------------
__global__ void norms_kernel(const float* __restrict__ v, float* __restrict__ o, int rows) {
    int row  = blockIdx.x * 4 + (threadIdx.x >> 6);
    int lane = threadIdx.x & 63;
    if (row >= rows) return;
    float2 x = reinterpret_cast<const float2*>(v)[(size_t)row * 64 + lane];
    float s = x.x * x.x + x.y * x.y;
    #pragma unroll
    for (int m = 32; m; m >>= 1) s += __shfl_xor(s, m, 64);
    if (lane == 0) o[row] = s;
}

// ------------- precompute: M -> bf16 hi/lo, tile-swizzled for global_load_lds -------------
// dst layout: tile(64 cells) contiguous 16KB; within: r*128 + ((b ^ (r&15))<<3) shorts
__global__ void convB_kernel(const float* __restrict__ M,
                             unsigned short* __restrict__ Bh_g,
                             unsigned short* __restrict__ Bl_g) {
    int idx  = blockIdx.x * 256 + threadIdx.x;   // 0..16383 (cell, 16B-block)
    int cell = idx >> 4;
    int b    = idx & 15;
    const float4* s = reinterpret_cast<const float4*>(M + (size_t)cell * D_DIM + b * 8);
    float4 v0 = s[0], v1 = s[1];
    float xv[8] = { v0.x, v0.y, v0.z, v0.w, v1.x, v1.y, v1.z, v1.w };
    short8 hs, ls;
    #pragma unroll
    for (int j = 0; j < 8; ++j) {
        unsigned short hb = f32_bf16_rtn(xv[j]);
        unsigned short lb = f32_bf16_rtn(xv[j] - bf16_f32(hb));
        hs[j] = (short)hb; ls[j] = (short)lb;
    }
    int tile = cell >> 6, r = cell & 63;
    int dst = tile * 8192 + r * 128 + ((b ^ (r & 15)) << 3);
    *reinterpret_cast<short8*>(&Bh_g[dst]) = hs;
    *reinterpret_cast<short8*>(&Bl_g[dst]) = ls;
}

// ------------- main: split-bf16 MFMA cdist + top-2 argmin + suspect list -------------
__global__ __launch_bounds__(256, 2)
void dist_kernel(const float* __restrict__ X,
                 const unsigned short* __restrict__ Bh_g,
                 const unsigned short* __restrict__ Bl_g,
                 const float* __restrict__ msq,
                 float* __restrict__ outD, int* __restrict__ cells32,
                 int* __restrict__ suspects, int* __restrict__ suspCount,
                 int N)
{
    __shared__ __align__(16) unsigned short Ah[64 * 128];
    __shared__ __align__(16) unsigned short Al[64 * 128];
    __shared__ __align__(16) unsigned short Bh[64 * 128];
    __shared__ __align__(16) unsigned short Bl[64 * 128];
    __shared__ float Axs[64];
    __shared__ unsigned long long sp1[64][2];
    __shared__ float              sm2[64][2];

    const int tid  = threadIdx.x;
    const int lane = tid & 63;
    const int wave = tid >> 6;
    const int q    = lane >> 4;    // quad id (0..3)
    const int l15  = lane & 15;
    const int w0   = wave & 1;     // col half (0..1)
    const int w1   = wave >> 1;    // row half (0..1)
    const int blockRow = blockIdx.x * 64;

    // ---- stage A: 64 rows x 128 k, f32 -> bf16 hi/lo, swizzled; fused row-norms ----
    #pragma unroll
    for (int p = 0; p < 4; ++p) {
        int r = p * 16 + (tid >> 4);    // 0..63
        int b = tid & 15;               // 16-byte block index (8 bf16)
        int gRow = blockRow + r;
        float4 v0 = make_float4(0.f, 0.f, 0.f, 0.f), v1 = v0;
        if (gRow < N) {
            const float4* s = reinterpret_cast<const float4*>(X + (size_t)gRow * D_DIM + b * 8);
            v0 = s[0]; v1 = s[1];
        }
        float xv[8] = { v0.x, v0.y, v0.z, v0.w, v1.x, v1.y, v1.z, v1.w };
        short8 hs, ls;
        float sq = 0.f;
        #pragma unroll
        for (int j = 0; j < 8; ++j) {
            sq += xv[j] * xv[j];
            unsigned short hb = f32_bf16_rtn(xv[j]);
            unsigned short lb = f32_bf16_rtn(xv[j] - bf16_f32(hb));
            hs[j] = (short)hb; ls[j] = (short)lb;
        }
        // reduce norm across the 16 lanes (b=0..15) sharing this row
        #pragma unroll
        for (int m = 1; m < 16; m <<= 1) sq += __shfl_xor(sq, m, 16);
        if (b == 0) Axs[r] = sq;
        int ad = r * 128 + ((b ^ (r & 15)) << 3);
        *reinterpret_cast<short8*>(&Ah[ad]) = hs;
        *reinterpret_cast<short8*>(&Al[ad]) = ls;
    }
    __syncthreads();

    // per-lane fixed output rows: local row = w1*32 + t*16 + q*4 + r
    float xs[8];
    #pragma unroll
    for (int t = 0; t < 2; ++t)
        #pragma unroll
        for (int r = 0; r < 4; ++r)
            xs[t * 4 + r] = Axs[w1 * 32 + t * 16 + q * 4 + r];

    float rminv[8]; float rmin2[8]; int rminc[8];
    #pragma unroll
    for (int i = 0; i < 8; ++i) { rminv[i] = INFINITY; rmin2[i] = INFINITY; rminc[i] = 0; }

    for (int ct = 0; ct < 16; ++ct) {
        if (ct) __syncthreads();   // previous tile's LDS reads done
        // ---- stage B: async copy precomputed bf16 tile (16KB hi + 16KB lo) ----
        {
            const char* bhg = (const char*)Bh_g + (size_t)ct * 16384 + wave * 4096 + lane * 16;
            const char* blg = (const char*)Bl_g + (size_t)ct * 16384 + wave * 4096 + lane * 16;
            char* bhl = (char*)Bh + wave * 4096;
            char* bll = (char*)Bl + wave * 4096;
            #pragma unroll
            for (int j = 0; j < 4; ++j) {
                gl2lds16(bhg + j * 1024, bhl + j * 1024);
                gl2lds16(blg + j * 1024, bll + j * 1024);
            }
        }
        __syncthreads();

        floatx4 acc[2][2];
        #pragma unroll
        for (int t = 0; t < 2; ++t)
            #pragma unroll
            for (int u = 0; u < 2; ++u)
                acc[t][u] = (floatx4){0.f, 0.f, 0.f, 0.f};

        #pragma unroll
        for (int kc = 0; kc < 4; ++kc) {
            int blk = kc * 4 + q;
            short8 ah[2], al[2], bh[2], bl[2];
            #pragma unroll
            for (int t = 0; t < 2; ++t) {
                int row = w1 * 32 + t * 16 + l15;     // row & 15 == l15
                int ad  = row * 128 + ((blk ^ l15) << 3);
                ah[t] = *reinterpret_cast<const short8*>(&Ah[ad]);
                al[t] = *reinterpret_cast<const short8*>(&Al[ad]);
            }
            #pragma unroll
            for (int u = 0; u < 2; ++u) {
                int col = w0 * 32 + u * 16 + l15;
                int ad  = col * 128 + ((blk ^ l15) << 3);
                bh[u] = *reinterpret_cast<const short8*>(&Bh[ad]);
                bl[u] = *reinterpret_cast<const short8*>(&Bl[ad]);
            }
            #pragma unroll
            for (int t = 0; t < 2; ++t)
                #pragma unroll
                for (int u = 0; u < 2; ++u) {
                    acc[t][u] = __builtin_amdgcn_mfma_f32_16x16x32_bf16(ah[t], bh[u], acc[t][u], 0, 0, 0);
                    acc[t][u] = __builtin_amdgcn_mfma_f32_16x16x32_bf16(ah[t], bl[u], acc[t][u], 0, 0, 0);
                    acc[t][u] = __builtin_amdgcn_mfma_f32_16x16x32_bf16(al[t], bh[u], acc[t][u], 0, 0, 0);
                }
        }

        // ---- epilogue: sq = |x|^2 + |m|^2 - 2*dot ; dist, NT store, running top-2 ----
        #pragma unroll
        for (int u = 0; u < 2; ++u) {
            int col = ct * 64 + w0 * 32 + u * 16 + l15;
            float ms = msq[col];
            #pragma unroll
            for (int t = 0; t < 2; ++t)
                #pragma unroll
                for (int r = 0; r < 4; ++r) {
                    int g  = blockRow + w1 * 32 + t * 16 + q * 4 + r;
                    int i  = t * 4 + r;
                    float sq = xs[i] + ms - 2.0f * acc[t][u][r];
                    float d  = sqrtf(fmaxf(sq, 0.0f));
                    if (g < N) __builtin_nontemporal_store(d, &outD[(size_t)g * C_CELLS + col]);
                    if (d < rminv[i]) { rmin2[i] = rminv[i]; rminv[i] = d; rminc[i] = col; }
                    else if (d < rmin2[i]) rmin2[i] = d;
                }
        }
    }

    // ---- per-row top-2 reduce across the 16 lanes sharing the same rows ----
    #pragma unroll
    for (int i = 0; i < 8; ++i) {
        union { float f; unsigned u; } bu; bu.f = rminv[i];
        unsigned long long p1 = ((unsigned long long)bu.u << 32) | (unsigned)rminc[i];
        float m2 = rmin2[i];
        #pragma unroll
        for (int m = 1; m < 16; m <<= 1) {
            unsigned long long o1 = __shfl_xor(p1, m, 16);
            float o2 = __shfl_xor(m2, m, 16);
            unsigned long long hi = (p1 > o1) ? p1 : o1;
            float hv = hi_f32(hi);
            p1 = (p1 < o1) ? p1 : o1;
            m2 = fminf(fminf(m2, o2), hv);
        }
        if (l15 == 0) {
            int lr = w1 * 32 + (i >> 2) * 16 + q * 4 + (i & 3);
            sp1[lr][w0] = p1; sm2[lr][w0] = m2;
        }
    }
    __syncthreads();
    // ---- cross-wave merge: one thread per row; write cell + suspect test ----
    if (tid < 64) {
        int g = blockRow + tid;
        if (g < N) {
            unsigned long long a = sp1[tid][0], b = sp1[tid][1];
            unsigned long long G1 = (a < b) ? a : b;
            unsigned long long hi = (a < b) ? b : a;
            float M2  = fminf(fminf(sm2[tid][0], sm2[tid][1]), hi_f32(hi));
            float g1v = hi_f32(G1);
            cells32[g] = (int)(G1 & 0xffffffffu);
            if (M2 - g1v < EPS_D) {
                int ix = atomicAdd(suspCount, 1);
                suspects[ix] = g;
            }
        }
    }
}

// ------------- refine: exact f64 argmin for near-tie rows -------------
__global__ __launch_bounds__(256)
void refine_kernel(const float* __restrict__ X, const float* __restrict__ M,
                   const int* __restrict__ suspects, const int* __restrict__ suspCount,
                   int* __restrict__ cells32)
{
    __shared__ double xd[128];
    __shared__ unsigned long long wres[4];
    int cnt = *suspCount;
    for (int s = blockIdx.x; s < cnt; s += gridDim.x) {
        int row = suspects[s];
        if (threadIdx.x < 128) xd[threadIdx.x] = (double)X[(size_t)row * D_DIM + threadIdx.x];
        __syncthreads();
        unsigned long long best = ~0ull;
        for (int c = threadIdx.x; c < C_CELLS; c += 256) {
            const float* mp = M + (size_t)c * D_DIM;
            double acc = 0.0;
            #pragma unroll 4
            for (int k = 0; k < D_DIM; ++k) {
                double diff = xd[k] - (double)mp[k];
                acc = fma(diff, diff, acc);
            }
            unsigned long long bits = (unsigned long long)__double_as_longlong(acc);
            unsigned long long pk = (bits & ~1023ull) | (unsigned long long)c;
            if (pk < best) best = pk;
        }
        #pragma unroll
        for (int m = 32; m; m >>= 1) {
            unsigned long long o = __shfl_xor(best, m, 64);
            if (o < best) best = o;
        }
        if ((threadIdx.x & 63) == 0) wres[threadIdx.x >> 6] = best;
        __syncthreads();
        if (threadIdx.x == 0) {
            unsigned long long b0 = wres[0] < wres[1] ? wres[0] : wres[1];
            unsigned long long b1 = wres[2] < wres[3] ? wres[2] : wres[3];
            unsigned long long b  = b0 < b1 ? b0 : b1;
            cells32[row] = (int)(b & 1023ull);
        }
        __syncthreads();
    }
}

// ------------- finalize: cells + scatter outputs (all written as f32 values) -------------
__global__ void post_kernel(const int* __restrict__ cells32,
                            const int* __restrict__ win,
                            const float* __restrict__ times,
                            const int* __restrict__ node_cell,
                            const float* __restrict__ node_time,
                            float* __restrict__ outCells,
                            float* __restrict__ outNC,
                            float* __restrict__ outNT,
                            int n, int numNodes)
{
    int j = blockIdx.x * blockDim.x + threadIdx.x;
    if (j < n) outCells[j] = (float)cells32[j];
    if (j < numNodes) {
        int w = win[j];
        float c, t;
        if (w >= 0) {
            c = (float)cells32[w];
            t = times[w];
        } else {
            c = (float)node_cell[j];
            t = node_time[j];
        }
        outNC[j] = c;
        outNT[j] = t;
    }
}

extern "C" void kernel_launch(void* const* d_in, const int* in_sizes, int n_in,
                              void* d_out, int out_size, void* d_ws, size_t ws_size,
                              hipStream_t stream)
{
    const float* X         = (const float*)d_in[0];   // [N, 128]
    const float* M         = (const float*)d_in[1];   // [1024, 128]
    const void*  nodes     = d_in[2];                 // [N] int32 or int64
    const float* times     = (const float*)d_in[3];   // [N]
    const int*   node_cell = (const int*)d_in[4];     // [numNodes]
    const float* node_time = (const float*)d_in[5];   // [numNodes]

    const int N        = in_sizes[3];
    const int numNodes = in_sizes[4];
    const int C        = in_sizes[1] / D_DIM;         // 1024

    // workspace layout (~5.7 MB)
    char* ws = (char*)d_ws;
    size_t off = 0;
    unsigned short* Bh_g = (unsigned short*)(ws + off); off += (size_t)C * D_DIM * 2;
    unsigned short* Bl_g = (unsigned short*)(ws + off); off += (size_t)C * D_DIM * 2;
    int* win      = (int*)(ws + off); off += (size_t)numNodes * 4;
    int* cells32  = (int*)(ws + off); off += (size_t)N * 4;
    int* suspects = (int*)(ws + off); off += (size_t)N * 4;
    float* msq    = (float*)(ws + off); off += (size_t)C * 4;
    int* flag     = (int*)(ws + off); off += 4;
    int* suspCount= (int*)(ws + off); off += 4;
    (void)ws_size; (void)n_in; (void)out_size;

    float* outD     = (float*)d_out;                  // [N,1024] distances
    float* outCells = outD + (size_t)N * C;           // [N] cells (as f32)
    float* outNC    = outCells + N;                   // [numNodes] node_cell (as f32)
    float* outNT    = outNC + numNodes;               // [numNodes] node_time

    init_kernel  <<<(numNodes + 255) / 256, 256, 0, stream>>>(win, flag, suspCount, numNodes);
    detect_kernel<<<(N + 255) / 256, 256, 0, stream>>>((const int*)nodes, N, flag);
    winner_kernel<<<(N + 255) / 256, 256, 0, stream>>>(nodes, N, flag, win);
    norms_kernel <<<(C + 3) / 4, 256, 0, stream>>>(M, msq, C);
    convB_kernel <<<(C * 16 + 255) / 256, 256, 0, stream>>>(M, Bh_g, Bl_g);
    dist_kernel  <<<(N + 63) / 64, 256, 0, stream>>>(X, Bh_g, Bl_g, msq, outD, cells32,
                                                     suspects, suspCount, N);
    refine_kernel<<<512, 256, 0, stream>>>(X, M, suspects, suspCount, cells32);
    post_kernel  <<<(numNodes + 255) / 256, 256, 0, stream>>>(cells32, win, times, node_cell,
                                                              node_time, outCells, outNC, outNT,
                                                              N, numNodes);
}